// Round 11
// baseline (836.821 us; speedup 1.0000x reference)
//
#include <hip/hip_runtime.h>
#include <hip/hip_bf16.h>
#include <stdint.h>

// QuantizedLinear: y = x @ (Wq * scale[:,None])^T + bias
// Round 11: i8 MFMA, 128x128 block, 4 waves (2Mx2N), BK=128, 2 blocks/CU.
// A-FRAGS DIRECT L2->REGISTERS (1 tile ahead, static X/Y dbuf); B via the
// r4-verified swizzled-LDS gload_lds path (dbuf 32 KiB only).
// Why: r4-r9 showed LDS BW (192KiB/CU per 2611 MFMA-cyc) caps MfmaUtil ~50%.
// r10 (B->regs) failed: B L2 working set 10.5MiB/XCD -> L3 BW wall (799us).
// A is the small operand: supertile swizzle keeps ~4 A-panels (2MiB) L2-
// resident; A-reg traffic 25 B/cyc << 56 L2 ceiling. LDS now carries only B:
// 96KiB/CU-dual-tile ~ 1156 cyc < MFMA 2611 cyc -> MFMA-bound at last.
// Sync per tile (ONE barrier): STAGE_B(t+1->bq) FIRST, then ALOAD(t+1) (so
// vmcnt(8) at tile end drains the 4 stages, keeps 8 A-loads flying); B-frag
// ds_reads + MFMA (compiler auto-waits: lgkm per-operand; vmcnt for Acur
// loaded a full tile ago = free); lgkm(0) [restage WAR] + vmcnt(8) + barrier.
// Hazards: restage bp@t+1 postdates t's lgkm(0)+barrier (WAR ok); reads of
// bq@t+1 postdate t's vmcnt(8)+barrier (RAW ok); A-regs compiler-tracked.

#define M_TOTAL 8192
#define K_TOTAL 4096
#define N_TOTAL 11008
#define NT 32
#define NBM 64
#define NBN 86

typedef __attribute__((ext_vector_type(4))) int int4v;

// ---------------- x quantization: per-row absmax -> int8 (verbatim) ----------------

__global__ __launch_bounds__(256) void quant_x_kernel(const float* __restrict__ x,
                                                      signed char* __restrict__ xq,
                                                      float* __restrict__ sx) {
    const int row = blockIdx.x;
    const int tid = threadIdx.x;
    const float* xr = x + (size_t)row * K_TOTAL + tid * 16;

    float4 v0 = reinterpret_cast<const float4*>(xr)[0];
    float4 v1 = reinterpret_cast<const float4*>(xr)[1];
    float4 v2 = reinterpret_cast<const float4*>(xr)[2];
    float4 v3 = reinterpret_cast<const float4*>(xr)[3];

    float m = 0.f;
    m = fmaxf(m, fmaxf(fmaxf(fabsf(v0.x), fabsf(v0.y)), fmaxf(fabsf(v0.z), fabsf(v0.w))));
    m = fmaxf(m, fmaxf(fmaxf(fabsf(v1.x), fabsf(v1.y)), fmaxf(fabsf(v1.z), fabsf(v1.w))));
    m = fmaxf(m, fmaxf(fmaxf(fabsf(v2.x), fabsf(v2.y)), fmaxf(fabsf(v2.z), fabsf(v2.w))));
    m = fmaxf(m, fmaxf(fmaxf(fabsf(v3.x), fabsf(v3.y)), fmaxf(fabsf(v3.z), fabsf(v3.w))));

    for (int d = 1; d < 64; d <<= 1) m = fmaxf(m, __shfl_xor(m, d));
    __shared__ float wm_[4];
    if ((tid & 63) == 0) wm_[tid >> 6] = m;
    __syncthreads();
    m = fmaxf(fmaxf(wm_[0], wm_[1]), fmaxf(wm_[2], wm_[3]));

    const float inv = (m > 0.f) ? (127.f / m) : 0.f;
    if (tid == 0) sx[row] = (m > 0.f) ? (m / 127.f) : 0.f;

    float tmp[16] = {v0.x,v0.y,v0.z,v0.w, v1.x,v1.y,v1.z,v1.w,
                     v2.x,v2.y,v2.z,v2.w, v3.x,v3.y,v3.z,v3.w};
    int q[16];
#pragma unroll
    for (int i = 0; i < 16; ++i) {
        int t = __float2int_rn(tmp[i] * inv);
        q[i] = t > 127 ? 127 : (t < -127 ? -127 : t);
    }
    int4v o;
#pragma unroll
    for (int w = 0; w < 4; ++w)
        o[w] = (q[w*4] & 255) | ((q[w*4+1] & 255) << 8) |
               ((q[w*4+2] & 255) << 16) | ((q[w*4+3] & 255) << 24);
    *reinterpret_cast<int4v*>(xq + (size_t)row * K_TOTAL + tid * 16) = o;
}

// ---------------- W unpack (verbatim) ----------------

__global__ __launch_bounds__(256) void cvt_w_kernel(const int* __restrict__ in,
                                                    signed char* __restrict__ out, int nitems) {
    bool is8 = false;
    for (int i = 0; i < 256; ++i) {
        int v = in[i];
        if (v < -127 || v > 127) { is8 = true; break; }
    }
    int stride = gridDim.x * blockDim.x;
    if (!is8) {
        for (int i = blockIdx.x * blockDim.x + threadIdx.x; i < nitems; i += stride) {
            const int* p = in + (size_t)i * 16;
            int4v o;
#pragma unroll
            for (int w = 0; w < 4; ++w)
                o[w] = (p[w*4] & 255) | ((p[w*4+1] & 255) << 8) |
                       ((p[w*4+2] & 255) << 16) | ((p[w*4+3] & 255) << 24);
            *reinterpret_cast<int4v*>(out + (size_t)i * 16) = o;
        }
    } else {
        const int4v* in16 = reinterpret_cast<const int4v*>(in);
        for (int i = blockIdx.x * blockDim.x + threadIdx.x; i < nitems; i += stride)
            *reinterpret_cast<int4v*>(out + (size_t)i * 16) = in16[i];
    }
}

// ---------------- 128x128 i8 GEMM: A L2->regs, B via swizzled LDS ----------------

#define GLOAD16(g, l) __builtin_amdgcn_global_load_lds( \
    (const __attribute__((address_space(1))) void*)(g), \
    (__attribute__((address_space(3))) void*)(l), 16, 0, 0)

// LDS (bytes): B only, dbuf p*16384; tile t in buf[t&1]. chunk = 8 rows =
// 1 KiB; wave wv stages chunks wv*4..wv*4+3. Swizzle: granule g at g^(row&7),
// inverse applied on global src (r4-verified).

#define STAGE_B(bsrc, buf)                                                      \
    _Pragma("unroll")                                                           \
    for (int i_ = 0; i_ < 4; ++i_)                                              \
        GLOAD16((bsrc) + soff[i_], (buf) + (c0 + i_) * 1024);
// A-frag loads, tile t -> dst[2][4] regs (8 x global_load_dwordx4, coalesced:
// 16 fr-rows x 64B chunk fully used per h)
#define ALOAD(dst, t)                                                           \
    _Pragma("unroll")                                                           \
    for (int h_ = 0; h_ < 2; ++h_) {                                            \
        _Pragma("unroll")                                                       \
        for (int m_ = 0; m_ < 4; ++m_)                                          \
            dst[h_][m_] = *(const int4v*)(aBase + (size_t)m_ * 16 * K_TOTAL +   \
                                          (size_t)(t) * 128 + h_ * 64);         \
    }
#define RD_B(dst, base, KX)                                                     \
    _Pragma("unroll")                                                           \
    for (int n_ = 0; n_ < 4; ++n_)                                              \
        dst[n_] = *(const int4v*)((base) + (wn * 64 + n_ * 16 + fr) * 128 + (KX));
#define SB __builtin_amdgcn_sched_barrier(0)

// One tile: stage B(t+1)->bq (issued FIRST), load A(t+1)->Anxt regs, compute
// tile t from Acur + bp, single drain+barrier.
#define TILE_BODY(bp, bq, Acur, Anxt, tnext)                                    \
    {                                                                           \
        if ((tnext) < NT) {                                                     \
            STAGE_B(bS + (size_t)(tnext) * 128, bq)                             \
            SB;                                                                 \
            ALOAD(Anxt, tnext)                                                  \
            SB;                                                                 \
        }                                                                       \
        int4v bf0[4], bf1[4];                                                   \
        RD_B(bf0, bp, kx0)                                                      \
        RD_B(bf1, bp, kx1)                                                      \
        __builtin_amdgcn_s_setprio(1);                                          \
        _Pragma("unroll")                                                       \
        for (int m_ = 0; m_ < 4; ++m_) {                                        \
            _Pragma("unroll")                                                   \
            for (int n_ = 0; n_ < 4; ++n_)                                      \
                acc[m_][n_] = __builtin_amdgcn_mfma_i32_16x16x64_i8(            \
                    Acur[0][m_], bf0[n_], acc[m_][n_], 0, 0, 0);                \
        }                                                                       \
        _Pragma("unroll")                                                       \
        for (int m_ = 0; m_ < 4; ++m_) {                                        \
            _Pragma("unroll")                                                   \
            for (int n_ = 0; n_ < 4; ++n_)                                      \
                acc[m_][n_] = __builtin_amdgcn_mfma_i32_16x16x64_i8(            \
                    Acur[1][m_], bf1[n_], acc[m_][n_], 0, 0, 0);                \
        }                                                                       \
        __builtin_amdgcn_s_setprio(0);                                          \
        asm volatile("s_waitcnt lgkmcnt(0)" ::: "memory");                      \
        if ((tnext) < NT) { asm volatile("s_waitcnt vmcnt(8)" ::: "memory"); }  \
        else              { asm volatile("s_waitcnt vmcnt(0)" ::: "memory"); }  \
        __builtin_amdgcn_s_barrier();                                           \
    }

__global__ __launch_bounds__(256, 2) void gemm_kernel(const unsigned char* __restrict__ A,
                                                      const unsigned char* __restrict__ B,
                                                      const float* __restrict__ sx,
                                                      const float* __restrict__ scale,
                                                      const float* __restrict__ bias,
                                                      float* __restrict__ C) {
    __shared__ unsigned char sh[32768];  // B dbuf only: 2 x 16 KiB -> 2 blocks/CU

    const int tid  = threadIdx.x;
    const int wv   = tid >> 6;      // 0..3
    const int lane = tid & 63;
    const int wm   = wv >> 1;       // 0..1
    const int wn   = wv & 1;        // 0..1

    // supertiled XCD swizzle (r4-verified, FETCH ~0.6GB): 5504 = 8 xcd * 688;
    // per-xcd 2 bands x 4bm, 4x4 supertiles (tail 4x2). Co-resident blocks
    // share 4 A-panels (2 MiB, L2-resident) and 4 B-panels.
    const int xcd = blockIdx.x & 7;
    const int l   = blockIdx.x >> 3;
    const int band = l / 344;
    const int lb   = l - band * 344;
    const int st   = lb >> 4;
    const int r    = lb & 15;
    int bm_l, bn;
    if (st < 21) { bm_l = band * 4 + (r >> 2); bn = st * 4 + (r & 3); }
    else         { bm_l = band * 4 + (r >> 1); bn = 84 + (r & 1); }
    const int bm = xcd * 8 + bm_l;

    // fragment geometry
    const int fr  = lane & 15;
    const int fq  = lane >> 4;
    const int swz = fr & 7;
    const int kx0 = (fq ^ swz) * 16;
    const int kx1 = ((4 + fq) ^ swz) * 16;

    // B staging source offsets (inverse-swizzled granule)
    const int c0 = wv * 4;
    const int rl = lane >> 3;
    const int sg = (lane & 7) ^ rl;
    int soff[4];
#pragma unroll
    for (int i = 0; i < 4; ++i)
        soff[i] = ((c0 + i) * 8 + rl) * K_TOTAL + sg * 16;

    // A per-lane base: row = bm*128 + wm*64 + m*16 + fr; fq picks 16B quarter
    const unsigned char* aBase = A + (size_t)(bm * 128 + wm * 64 + fr) * K_TOTAL + fq * 16;
    const unsigned char* bS = B + (size_t)bn * 128 * K_TOTAL;
    unsigned char* buf0 = sh;
    unsigned char* buf1 = sh + 16384;

    int4v acc[4][4] = {};
    int4v AX[2][4], AY[2][4];

    // ---- prologue: B(0)->buf0 (4 stages), A(0)->AX (8 loads) ----
    STAGE_B(bS, buf0)
    SB;
    ALOAD(AX, 0)
    SB;
    asm volatile("s_waitcnt vmcnt(8)" ::: "memory");   // B(0) landed; AX in flight
    __builtin_amdgcn_s_barrier();

    // ---- main loop: static dbuf + static A-reg naming (rule #20) ----
#pragma unroll 1
    for (int u = 0; u < NT / 2; ++u) {
        TILE_BODY(buf0, buf1, AX, AY, 2 * u + 1)
        TILE_BODY(buf1, buf0, AY, AX, 2 * u + 2)
    }

    // ---- epilogue: y = acc * sx[row]*scale[col] + bias[col] ----
    const int crow0 = bm * 128 + wm * 64;
    const int ccol0 = bn * 128 + wn * 64;
    float scv[4], bsv[4];
#pragma unroll
    for (int n = 0; n < 4; ++n) {
        const int col = ccol0 + n * 16 + fr;
        scv[n] = scale[col];
        bsv[n] = bias[col];
    }
#pragma unroll
    for (int fm = 0; fm < 4; ++fm) {
#pragma unroll
        for (int j = 0; j < 4; ++j) {
            const int row = crow0 + fm * 16 + fq * 4 + j;
            const float sr = sx[row];
            float* cp = C + (size_t)row * N_TOTAL + ccol0 + fr;
#pragma unroll
            for (int n = 0; n < 4; ++n)
                cp[n * 16] = (float)acc[fm][n][j] * (sr * scv[n]) + bsv[n];
        }
    }
}

// ---------------- fallback (ws too small): tiled f32 vector GEMM ----------------

__global__ __launch_bounds__(256) void gemm_fallback(const float* __restrict__ x,
                                                     const int* __restrict__ w,
                                                     const float* __restrict__ scale,
                                                     const float* __restrict__ bias,
                                                     float* __restrict__ C) {
    bool is8 = false;
    for (int i = 0; i < 256; ++i) {
        int v = w[i];
        if (v < -127 || v > 127) { is8 = true; break; }
    }
    const signed char* w8 = (const signed char*)w;

    __shared__ float As[64][16];
    __shared__ float Bs[64][16];
    const int nbn = N_TOTAL / 64;
    const int bm = blockIdx.x / nbn;
    const int bn = blockIdx.x % nbn;
    const int tid = threadIdx.x;
    const int tx = tid & 15, ty = tid >> 4;

    float acc[4][4] = {};
    for (int kt = 0; kt < K_TOTAL; kt += 16) {
        for (int i = 0; i < 4; ++i) {
            int idx = tid + i * 256;
            int rr = idx >> 4, cc = idx & 15;
            As[rr][cc] = x[(size_t)(bm * 64 + rr) * K_TOTAL + kt + cc];
            size_t widx = (size_t)(bn * 64 + rr) * K_TOTAL + kt + cc;
            Bs[rr][cc] = is8 ? (float)w8[widx] : (float)w[widx];
        }
        __syncthreads();
        for (int kk = 0; kk < 16; ++kk) {
            float a[4], b[4];
            for (int i = 0; i < 4; ++i) a[i] = As[ty * 4 + i][kk];
            for (int j = 0; j < 4; ++j) b[j] = Bs[tx * 4 + j][kk];
            for (int i = 0; i < 4; ++i)
                for (int j = 0; j < 4; ++j) acc[i][j] += a[i] * b[j];
        }
        __syncthreads();
    }
    for (int j = 0; j < 4; ++j) {
        int col = bn * 64 + tx * 4 + j;
        float s = scale[col], bb = bias[col];
        for (int i = 0; i < 4; ++i) {
            int row = bm * 64 + ty * 4 + i;
            C[(size_t)row * N_TOTAL + col] = acc[i][j] * s + bb;
        }
    }
}

// ---------------- launch ----------------

extern "C" void kernel_launch(void* const* d_in, const int* in_sizes, int n_in,
                              void* d_out, int out_size, void* d_ws, size_t ws_size,
                              hipStream_t stream) {
    const float* x     = (const float*)d_in[0];
    const int*   wq    = (const int*)d_in[1];
    const float* scale = (const float*)d_in[2];
    const float* bias  = (const float*)d_in[3];
    float*       out   = (float*)d_out;

    const size_t x_bytes = (size_t)M_TOTAL * K_TOTAL;
    const size_t w_bytes = (size_t)N_TOTAL * K_TOTAL;
    const size_t need = x_bytes + w_bytes + M_TOTAL * sizeof(float);

    if (ws_size >= need) {
        signed char* xq = (signed char*)d_ws;
        signed char* wb = (signed char*)d_ws + x_bytes;
        float*       sx = (float*)((char*)d_ws + x_bytes + w_bytes);

        quant_x_kernel<<<M_TOTAL, 256, 0, stream>>>(x, xq, sx);
        cvt_w_kernel<<<2048, 256, 0, stream>>>(wq, wb, (int)(w_bytes / 16));
        dim3 grid(NBM * NBN);  // 5504
        gemm_kernel<<<grid, 256, 0, stream>>>((const unsigned char*)xq,
                                              (const unsigned char*)wb,
                                              sx, scale, bias, out);
    } else {
        dim3 grid((M_TOTAL / 64) * (N_TOTAL / 64));
        gemm_fallback<<<grid, 256, 0, stream>>>(x, wq, scale, bias, out);
    }
}

// Round 12
// 462.394 us; speedup vs baseline: 1.8098x; 1.8098x over previous
//
#include <hip/hip_runtime.h>
#include <hip/hip_bf16.h>
#include <stdint.h>

// QuantizedLinear: y = x @ (Wq * scale[:,None])^T + bias
// Round 12: r4's GEMM VERBATIM (best measured: 373us, MfmaUtil 47, at ~89-97%
// of its LDS-BW floor -- r7-r11 variants all regressed) + FUSED prep launch
// (x row-quant blocks 0..8191, W unpack blocks 8192..10239 in one kernel so
// the two streaming passes overlap; saves ~25-35us of serialized launches).
// GEMM structure: i8 MFMA 16x16x64, 128x128 tile, BK=128, 4 waves (2Mx2N),
// 64 KiB LDS dbuf -> 2 blocks/CU (TLP covers read/MFMA/epilogue overlap),
// XOR-swizzled LDS (conflicts 0), supertiled XCD swizzle, counted vmcnt.

#define M_TOTAL 8192
#define K_TOTAL 4096
#define N_TOTAL 11008
#define NT 32
#define NBM 64
#define NBN 86

typedef __attribute__((ext_vector_type(4))) int int4v;

// ---------------- fused prep: x row-quant + W unpack, one launch ----------------

__global__ __launch_bounds__(256) void prep_kernel(const float* __restrict__ x,
                                                   const int* __restrict__ wq,
                                                   signed char* __restrict__ xq,
                                                   signed char* __restrict__ wb,
                                                   float* __restrict__ sx) {
    __shared__ float wm_[4];
    if (blockIdx.x < M_TOTAL) {
        // ---- per-row absmax quant of x (r4 logic verbatim) ----
        const int row = blockIdx.x;
        const int tid = threadIdx.x;
        const float* xr = x + (size_t)row * K_TOTAL + tid * 16;

        float4 v0 = reinterpret_cast<const float4*>(xr)[0];
        float4 v1 = reinterpret_cast<const float4*>(xr)[1];
        float4 v2 = reinterpret_cast<const float4*>(xr)[2];
        float4 v3 = reinterpret_cast<const float4*>(xr)[3];

        float m = 0.f;
        m = fmaxf(m, fmaxf(fmaxf(fabsf(v0.x), fabsf(v0.y)), fmaxf(fabsf(v0.z), fabsf(v0.w))));
        m = fmaxf(m, fmaxf(fmaxf(fabsf(v1.x), fabsf(v1.y)), fmaxf(fabsf(v1.z), fabsf(v1.w))));
        m = fmaxf(m, fmaxf(fmaxf(fabsf(v2.x), fabsf(v2.y)), fmaxf(fabsf(v2.z), fabsf(v2.w))));
        m = fmaxf(m, fmaxf(fmaxf(fabsf(v3.x), fabsf(v3.y)), fmaxf(fabsf(v3.z), fabsf(v3.w))));

        for (int d = 1; d < 64; d <<= 1) m = fmaxf(m, __shfl_xor(m, d));
        if ((tid & 63) == 0) wm_[tid >> 6] = m;
        __syncthreads();
        m = fmaxf(fmaxf(wm_[0], wm_[1]), fmaxf(wm_[2], wm_[3]));

        const float inv = (m > 0.f) ? (127.f / m) : 0.f;
        if (tid == 0) sx[row] = (m > 0.f) ? (m / 127.f) : 0.f;

        float tmp[16] = {v0.x,v0.y,v0.z,v0.w, v1.x,v1.y,v1.z,v1.w,
                         v2.x,v2.y,v2.z,v2.w, v3.x,v3.y,v3.z,v3.w};
        int q[16];
#pragma unroll
        for (int i = 0; i < 16; ++i) {
            int t = __float2int_rn(tmp[i] * inv);
            q[i] = t > 127 ? 127 : (t < -127 ? -127 : t);
        }
        int4v o;
#pragma unroll
        for (int w = 0; w < 4; ++w)
            o[w] = (q[w*4] & 255) | ((q[w*4+1] & 255) << 8) |
                   ((q[w*4+2] & 255) << 16) | ((q[w*4+3] & 255) << 24);
        *reinterpret_cast<int4v*>(xq + (size_t)row * K_TOTAL + tid * 16) = o;
    } else {
        // ---- W unpack: int32 wire (or packed int8) -> i8 (r4 logic) ----
        const int nitems = (int)(((size_t)N_TOTAL * K_TOTAL) / 16);
        bool is8 = false;
        for (int i = 0; i < 256; ++i) {
            int v = wq[i];
            if (v < -127 || v > 127) { is8 = true; break; }
        }
        const int nblk = gridDim.x - M_TOTAL;
        const int stride = nblk * blockDim.x;
        const int start = (blockIdx.x - M_TOTAL) * blockDim.x + threadIdx.x;
        if (!is8) {
            for (int i = start; i < nitems; i += stride) {
                const int* p = wq + (size_t)i * 16;
                int4v o;
#pragma unroll
                for (int w = 0; w < 4; ++w)
                    o[w] = (p[w*4] & 255) | ((p[w*4+1] & 255) << 8) |
                           ((p[w*4+2] & 255) << 16) | ((p[w*4+3] & 255) << 24);
                *reinterpret_cast<int4v*>(wb + (size_t)i * 16) = o;
            }
        } else {
            const int4v* in16 = reinterpret_cast<const int4v*>(wq);
            for (int i = start; i < nitems; i += stride)
                *reinterpret_cast<int4v*>(wb + (size_t)i * 16) = in16[i];
        }
    }
}

// ---------------- 128x128 i8 GEMM, 2 blocks/CU (r4 verbatim) ----------------

#define GLOAD16(g, l) __builtin_amdgcn_global_load_lds( \
    (const __attribute__((address_space(1))) void*)(g), \
    (__attribute__((address_space(3))) void*)(l), 16, 0, 0)

// LDS (bytes): buf p*32768 + {A: [0,16K) | B: [16K,32K)}. Tile = 128 rows x 128 B.
// chunk = 8 rows = 1 KiB; 16 chunks/operand; wave wv stages chunks wv*4..wv*4+3.
// Swizzle: 16B granule g stored at g ^ (row&7); inverse applied on global src.

__global__ __launch_bounds__(256, 2) void gemm_kernel(const unsigned char* __restrict__ A,
                                                      const unsigned char* __restrict__ B,
                                                      const float* __restrict__ sx,
                                                      const float* __restrict__ scale,
                                                      const float* __restrict__ bias,
                                                      float* __restrict__ C) {
    __shared__ unsigned char sh[65536];  // 64 KiB -> 2 blocks/CU

    const int tid  = threadIdx.x;
    const int wv   = tid >> 6;      // 0..3
    const int lane = tid & 63;
    const int wm   = wv >> 1;       // 0..1
    const int wn   = wv & 1;        // 0..1

    // supertiled XCD swizzle: 5504 = 8 xcd * 688; per-xcd 8 bm x 86 bn in
    // 2 bands of 4 bm; 4x4 supertiles (tail 4x2) so co-resident blocks share panels.
    const int xcd = blockIdx.x & 7;
    const int l   = blockIdx.x >> 3;        // 0..687
    const int band = l / 344;
    const int lb   = l - band * 344;
    const int st   = lb >> 4;
    const int r    = lb & 15;
    int bm_l, bn;
    if (st < 21) { bm_l = band * 4 + (r >> 2); bn = st * 4 + (r & 3); }
    else         { bm_l = band * 4 + (r >> 1); bn = 84 + (r & 1); }
    const int bm = xcd * 8 + bm_l;

    // fragment-read geometry (byte offsets)
    const int fr  = lane & 15;
    const int fq  = lane >> 4;
    const int swz = fr & 7;
    const int kx0 = (fq ^ swz) * 16;         // K granules 0..3
    const int kx1 = ((4 + fq) ^ swz) * 16;   // K granules 4..7

    // staging source offsets (inverse-swizzled granule)
    const int c0 = wv * 4;
    const int rl = lane >> 3;
    const int sg = (lane & 7) ^ rl;
    size_t soff[4];
#pragma unroll
    for (int i = 0; i < 4; ++i)
        soff[i] = (size_t)((c0 + i) * 8 + rl) * K_TOTAL + sg * 16;

    const unsigned char* aS = A + (size_t)bm * 128 * K_TOTAL;
    const unsigned char* bS = B + (size_t)bn * 128 * K_TOTAL;

    int4v acc[4][4] = {};

    // ---- prologue: A(0)->buf0, B(0)->buf0, B(1)->buf1 (12 loads) ----
#pragma unroll
    for (int i = 0; i < 4; ++i) GLOAD16(aS + soff[i],       sh + (c0 + i) * 1024);
#pragma unroll
    for (int i = 0; i < 4; ++i) GLOAD16(bS + soff[i],       sh + 16384 + (c0 + i) * 1024);
#pragma unroll
    for (int i = 0; i < 4; ++i) GLOAD16(bS + 128 + soff[i], sh + 32768 + 16384 + (c0 + i) * 1024);
    asm volatile("s_waitcnt vmcnt(4)" ::: "memory");  // A(0),B(0) landed; B(1) in flight
    __builtin_amdgcn_s_barrier();

    // ---- main loop: 2 phases/tile; stage A(t+1)@P0 (other parity), B(t+2)@P1 (same parity) ----
#pragma unroll 1
    for (int t = 0; t < NT; ++t) {
        const int p = t & 1;
        const unsigned char* rd  = sh + (p << 15);
        unsigned char* stA = sh + ((p ^ 1) << 15);           // A(t+1)
        unsigned char* stB = sh + (p << 15) + 16384;         // B(t+2), same parity
        const unsigned char* aSrc = aS + (size_t)(t + 1) * 128;
        const unsigned char* bSrc = bS + (size_t)(t + 2) * 128;

        int4v af0[4], af1[4], bf0[4], bf1[4];

        // ---- P0: read af(K0) + bf(K0,K1); stage A(t+1); MFMA K0 ----
#pragma unroll
        for (int i = 0; i < 4; ++i) {
            const unsigned char* ap = rd + (wm * 64 + i * 16 + fr) * 128;
            af0[i] = *(const int4v*)(ap + kx0);
        }
#pragma unroll
        for (int n = 0; n < 4; ++n) {
            const unsigned char* bp = rd + 16384 + (wn * 64 + n * 16 + fr) * 128;
            bf0[n] = *(const int4v*)(bp + kx0);
            bf1[n] = *(const int4v*)(bp + kx1);
        }
        if (t + 1 < NT) {
#pragma unroll
            for (int i = 0; i < 4; ++i)
                GLOAD16(aSrc + soff[i], stA + (c0 + i) * 1024);
        }
        __builtin_amdgcn_s_barrier();
        asm volatile("s_waitcnt lgkmcnt(0)" ::: "memory");
        __builtin_amdgcn_s_setprio(1);
#pragma unroll
        for (int i = 0; i < 4; ++i)
#pragma unroll
            for (int n = 0; n < 4; ++n)
                acc[i][n] = __builtin_amdgcn_mfma_i32_16x16x64_i8(af0[i], bf0[n], acc[i][n], 0, 0, 0);
        __builtin_amdgcn_s_setprio(0);
        __builtin_amdgcn_s_barrier();

        // ---- P1: read af(K1); stage B(t+2); MFMA K1 ----
#pragma unroll
        for (int i = 0; i < 4; ++i) {
            const unsigned char* ap = rd + (wm * 64 + i * 16 + fr) * 128;
            af1[i] = *(const int4v*)(ap + kx1);
        }
        if (t + 2 < NT) {
#pragma unroll
            for (int i = 0; i < 4; ++i)
                GLOAD16(bSrc + soff[i], stB + (c0 + i) * 1024);
        }
        __builtin_amdgcn_s_barrier();
        asm volatile("s_waitcnt lgkmcnt(0)" ::: "memory");
        __builtin_amdgcn_s_setprio(1);
#pragma unroll
        for (int i = 0; i < 4; ++i)
#pragma unroll
            for (int n = 0; n < 4; ++n)
                acc[i][n] = __builtin_amdgcn_mfma_i32_16x16x64_i8(af1[i], bf1[n], acc[i][n], 0, 0, 0);
        __builtin_amdgcn_s_setprio(0);
        if (t + 2 < NT) { asm volatile("s_waitcnt vmcnt(4)" ::: "memory"); }
        else            { asm volatile("s_waitcnt vmcnt(0)" ::: "memory"); }
        __builtin_amdgcn_s_barrier();
    }

    // ---- epilogue: y = acc * sx[row]*scale[col] + bias[col] ----
    const int crow0 = bm * 128 + wm * 64;
    const int ccol0 = bn * 128 + wn * 64;
    float scv[4], bsv[4];
#pragma unroll
    for (int n = 0; n < 4; ++n) {
        const int col = ccol0 + n * 16 + fr;
        scv[n] = scale[col];
        bsv[n] = bias[col];
    }
#pragma unroll
    for (int fm = 0; fm < 4; ++fm) {
#pragma unroll
        for (int j = 0; j < 4; ++j) {
            const int row = crow0 + fm * 16 + fq * 4 + j;
            const float sr = sx[row];
            float* cp = C + (size_t)row * N_TOTAL + ccol0 + fr;
#pragma unroll
            for (int n = 0; n < 4; ++n)
                cp[n * 16] = (float)acc[fm][n][j] * (sr * scv[n]) + bsv[n];
        }
    }
}

// ---------------- fallback (ws too small): tiled f32 vector GEMM ----------------

__global__ __launch_bounds__(256) void gemm_fallback(const float* __restrict__ x,
                                                     const int* __restrict__ w,
                                                     const float* __restrict__ scale,
                                                     const float* __restrict__ bias,
                                                     float* __restrict__ C) {
    bool is8 = false;
    for (int i = 0; i < 256; ++i) {
        int v = w[i];
        if (v < -127 || v > 127) { is8 = true; break; }
    }
    const signed char* w8 = (const signed char*)w;

    __shared__ float As[64][16];
    __shared__ float Bs[64][16];
    const int nbn = N_TOTAL / 64;
    const int bm = blockIdx.x / nbn;
    const int bn = blockIdx.x % nbn;
    const int tid = threadIdx.x;
    const int tx = tid & 15, ty = tid >> 4;

    float acc[4][4] = {};
    for (int kt = 0; kt < K_TOTAL; kt += 16) {
        for (int i = 0; i < 4; ++i) {
            int idx = tid + i * 256;
            int rr = idx >> 4, cc = idx & 15;
            As[rr][cc] = x[(size_t)(bm * 64 + rr) * K_TOTAL + kt + cc];
            size_t widx = (size_t)(bn * 64 + rr) * K_TOTAL + kt + cc;
            Bs[rr][cc] = is8 ? (float)w8[widx] : (float)w[widx];
        }
        __syncthreads();
        for (int kk = 0; kk < 16; ++kk) {
            float a[4], b[4];
            for (int i = 0; i < 4; ++i) a[i] = As[ty * 4 + i][kk];
            for (int j = 0; j < 4; ++j) b[j] = Bs[tx * 4 + j][kk];
            for (int i = 0; i < 4; ++i)
                for (int j = 0; j < 4; ++j) acc[i][j] += a[i] * b[j];
        }
        __syncthreads();
    }
    for (int j = 0; j < 4; ++j) {
        int col = bn * 64 + tx * 4 + j;
        float s = scale[col], bb = bias[col];
        for (int i = 0; i < 4; ++i) {
            int row = bm * 64 + ty * 4 + i;
            C[(size_t)row * N_TOTAL + col] = acc[i][j] * s + bb;
        }
    }
}

// ---------------- launch ----------------

extern "C" void kernel_launch(void* const* d_in, const int* in_sizes, int n_in,
                              void* d_out, int out_size, void* d_ws, size_t ws_size,
                              hipStream_t stream) {
    const float* x     = (const float*)d_in[0];
    const int*   wq    = (const int*)d_in[1];
    const float* scale = (const float*)d_in[2];
    const float* bias  = (const float*)d_in[3];
    float*       out   = (float*)d_out;

    const size_t x_bytes = (size_t)M_TOTAL * K_TOTAL;
    const size_t w_bytes = (size_t)N_TOTAL * K_TOTAL;
    const size_t need = x_bytes + w_bytes + M_TOTAL * sizeof(float);

    if (ws_size >= need) {
        signed char* xq = (signed char*)d_ws;
        signed char* wb = (signed char*)d_ws + x_bytes;
        float*       sx = (float*)((char*)d_ws + x_bytes + w_bytes);

        prep_kernel<<<M_TOTAL + 2048, 256, 0, stream>>>(x, wq, xq, wb, sx);
        dim3 grid(NBM * NBN);  // 5504
        gemm_kernel<<<grid, 256, 0, stream>>>((const unsigned char*)xq,
                                              (const unsigned char*)wb,
                                              sx, scale, bias, out);
    } else {
        dim3 grid((M_TOTAL / 64) * (N_TOTAL / 64));
        gemm_fallback<<<grid, 256, 0, stream>>>(x, wq, scale, bias, out);
    }
}